// Round 6
// baseline (1581.070 us; speedup 1.0000x reference)
//
#include <hip/hip_runtime.h>

#define IN_F 48
#define EDGE_F 32
#define HID_F 128
#define OUT_F 64

typedef float f4nt __attribute__((ext_vector_type(4)));  // NT-builtin-compatible float4

// ---------------- counting-sort-by-dst preprocessing ----------------

__global__ void k_hist(const int* __restrict__ dst, int* __restrict__ cnt, int E) {
    int e = blockIdx.x * 256 + threadIdx.x;
    if (e < E) atomicAdd(&cnt[dst[e]], 1);
}

// inclusive scan of 1024-chunk -> offsets[1+g]; chunk totals -> blksum; zeroes cnt for reuse as cursor
__global__ void k_scan1(int* __restrict__ cnt, int* __restrict__ offsets,
                        int* __restrict__ blksum, int N) {
    __shared__ int sh[1024];
    int tid = threadIdx.x;
    int g = blockIdx.x * 1024 + tid;
    sh[tid] = (g < N) ? cnt[g] : 0;
    if (g < N) cnt[g] = 0;   // cursor reset folded in
    __syncthreads();
#pragma unroll
    for (int off = 1; off < 1024; off <<= 1) {
        int t = (tid >= off) ? sh[tid - off] : 0;
        __syncthreads();
        sh[tid] += t;
        __syncthreads();
    }
    if (g < N) offsets[1 + g] = sh[tid];
    if (tid == 1023) blksum[blockIdx.x] = sh[tid];
}

__global__ void k_scan2(int* __restrict__ blksum, int nb) {
    __shared__ int sh[256];
    int tid = threadIdx.x;
    int orig = (tid < nb) ? blksum[tid] : 0;
    sh[tid] = orig;
    __syncthreads();
#pragma unroll
    for (int off = 1; off < 256; off <<= 1) {
        int t = (tid >= off) ? sh[tid - off] : 0;
        __syncthreads();
        sh[tid] += t;
        __syncthreads();
    }
    if (tid < nb) blksum[tid] = sh[tid] - orig;  // exclusive
}

__global__ void k_scan3(int* __restrict__ offsets, const int* __restrict__ blksum, int N) {
    int g = blockIdx.x * 1024 + threadIdx.x;
    if (g < N) offsets[1 + g] += blksum[blockIdx.x];
    if (g == 0) offsets[0] = 0;
}

// ---------------- fill: one 8B NT scattered store per edge ----------------
__global__ void k_fill(const int* __restrict__ dst, const int* __restrict__ src,
                       const int* __restrict__ offsets, int* __restrict__ cursor,
                       long long* __restrict__ eidsrc, int E) {
    int e = blockIdx.x * 256 + threadIdx.x;
    if (e >= E) return;
    int d = dst[e];
    int s = src[e];
    int p = atomicAdd(&cursor[d], 1);
    int pos = offsets[d] + p;
    long long v = ((long long)s << 32) | (unsigned int)e;
    __builtin_nontemporal_store(v, eidsrc + pos);
}

// ---------------- edge encoder: random efeat read, sequential NT msort write ----------------
__global__ __launch_bounds__(256) void k_edge_msg(
    const float* __restrict__ efeat, const float* __restrict__ nfeat,
    const long long* __restrict__ eidsrc,
    const float* __restrict__ We, const float* __restrict__ be,
    float* __restrict__ msort, int E) {
    int i = blockIdx.x * 256 + threadIdx.x;
    if (i >= E) return;
    long long es = eidsrc[i];
    int e = (int)es;
    int s = (int)(es >> 32);

    float ef[EDGE_F];
    const f4nt* ef4 = (const f4nt*)(efeat + (size_t)e * EDGE_F);
#pragma unroll
    for (int q = 0; q < EDGE_F / 4; ++q) {
        f4nt v = __builtin_nontemporal_load(ef4 + q);
        ef[4 * q + 0] = v.x; ef[4 * q + 1] = v.y; ef[4 * q + 2] = v.z; ef[4 * q + 3] = v.w;
    }
    float acc[IN_F];
#pragma unroll
    for (int j = 0; j < IN_F; ++j) acc[j] = be[j];          // wave-uniform -> s_load
#pragma unroll
    for (int k = 0; k < EDGE_F; ++k) {
        float ek = ef[k];
#pragma unroll
        for (int j = 0; j < IN_F; ++j) acc[j] = fmaf(ek, We[k * IN_F + j], acc[j]);
    }
    const float4* n4 = (const float4*)(nfeat + (size_t)s * IN_F);
    f4nt* o4 = (f4nt*)(msort + (size_t)i * IN_F);
#pragma unroll
    for (int q = 0; q < IN_F / 4; ++q) {
        float4 nv = n4[q];
        f4nt ov;
        ov.x = fmaxf(acc[4 * q + 0], 0.0f) * nv.x;
        ov.y = fmaxf(acc[4 * q + 1], 0.0f) * nv.y;
        ov.z = fmaxf(acc[4 * q + 2], 0.0f) * nv.z;
        ov.w = fmaxf(acc[4 * q + 3], 0.0f) * nv.w;
        __builtin_nontemporal_store(ov, o4 + q);
    }
}

// ---------------- layer-1 mean (stream msort) + build hcat=[nfeat,hn0] ----------------
__global__ __launch_bounds__(256) void k_gather48m(
    const float* __restrict__ msort, const float* __restrict__ nfeat,
    const int* __restrict__ offsets, float* __restrict__ hcat, int N) {
    int node = blockIdx.x * 4 + (threadIdx.x >> 6);
    int j = threadIdx.x & 63;
    if (node >= N) return;
    int jj = (j < IN_F) ? j : 0;
    int s0 = offsets[node], s1 = offsets[node + 1];
    float ivn = 1.0f / (float)max(s1 - s0, 1);
    float sum = 0.0f;
    int i = s0;
    for (; i + 4 <= s1; i += 4) {
        float a = __builtin_nontemporal_load(msort + (size_t)(i + 0) * IN_F + jj);
        float b = __builtin_nontemporal_load(msort + (size_t)(i + 1) * IN_F + jj);
        float c = __builtin_nontemporal_load(msort + (size_t)(i + 2) * IN_F + jj);
        float d = __builtin_nontemporal_load(msort + (size_t)(i + 3) * IN_F + jj);
        sum += (a + b) + (c + d);
    }
    for (; i < s1; ++i) sum += __builtin_nontemporal_load(msort + (size_t)i * IN_F + jj);
    if (j < IN_F) {
        hcat[(size_t)node * 96 + IN_F + j] = sum * ivn;                // hn0 half
        hcat[(size_t)node * 96 + j] = nfeat[(size_t)node * IN_F + j];  // nfeat half
    }
}

// ---------------- layer-2 neighbor mean over hcat (96-wide), wave-per-node ----------------
// lane j owns col j; lanes j<32 additionally own col 64+j.
__global__ __launch_bounds__(256) void k_gather96(
    const float* __restrict__ hcat, const long long* __restrict__ eidsrc,
    const int* __restrict__ offsets, float* __restrict__ hn1m, int N) {
    int node = blockIdx.x * 4 + (threadIdx.x >> 6);
    int j = threadIdx.x & 63;
    if (node >= N) return;
    const float* tabA = hcat + j;         // cols 0..63
    const float* tabB = hcat + 64 + j;    // cols 64..95 (j<32)
    int s0 = offsets[node], s1 = offsets[node + 1];
    float ivn = 1.0f / (float)max(s1 - s0, 1);
    float sA = 0.0f, sB = 0.0f;
    int i = s0;
    for (; i + 4 <= s1; i += 4) {
        int sa = (int)(eidsrc[i] >> 32);
        int sb = (int)(eidsrc[i + 1] >> 32);
        int sc = (int)(eidsrc[i + 2] >> 32);
        int sd = (int)(eidsrc[i + 3] >> 32);
        float a0 = tabA[(size_t)sa * 96], a1 = tabA[(size_t)sb * 96];
        float a2 = tabA[(size_t)sc * 96], a3 = tabA[(size_t)sd * 96];
        sA += (a0 + a1) + (a2 + a3);
        if (j < 32) {
            float b0 = tabB[(size_t)sa * 96], b1 = tabB[(size_t)sb * 96];
            float b2 = tabB[(size_t)sc * 96], b3 = tabB[(size_t)sd * 96];
            sB += (b0 + b1) + (b2 + b3);
        }
    }
    for (; i < s1; ++i) {
        int sa = (int)(eidsrc[i] >> 32);
        sA += tabA[(size_t)sa * 96];
        if (j < 32) sB += tabB[(size_t)sa * 96];
    }
    hn1m[(size_t)node * 96 + j] = sA * ivn;
    if (j < 32) hn1m[(size_t)node * 96 + 64 + j] = sB * ivn;
}

// ---------------- mm1: h1 = relu(hcat@W1s + hn1m@W1n + b1), 4 rows/wave ----------------
__global__ __launch_bounds__(256) void k_mm1(
    const float* __restrict__ hcat, const float* __restrict__ hn1m,
    const float* __restrict__ W1s, const float* __restrict__ W1n,
    const float* __restrict__ b1, float* __restrict__ h1, int N) {
    __shared__ float xs[16][192];
    int wv = threadIdx.x >> 6, lane = threadIdx.x & 63;
    int base = blockIdx.x * 16;
#pragma unroll
    for (int rr = 0; rr < 4; ++rr) {
        int row = base + wv * 4 + rr;
        int r = row < N ? row : N - 1;
#pragma unroll
        for (int kk = 0; kk < 3; ++kk) {
            int k = lane + kk * 64;
            float v = (k < 96) ? hcat[(size_t)r * 96 + k] : hn1m[(size_t)r * 96 + (k - 96)];
            xs[wv * 4 + rr][k] = v;
        }
    }
    __syncthreads();
    const float* x0 = xs[wv * 4 + 0];
    const float* x1 = xs[wv * 4 + 1];
    const float* x2 = xs[wv * 4 + 2];
    const float* x3 = xs[wv * 4 + 3];
    int c0 = lane, c1 = lane + 64;
    float a00 = b1[c0], a01 = b1[c1];
    float a10 = a00, a11 = a01, a20 = a00, a21 = a01, a30 = a00, a31 = a01;
#pragma unroll 4
    for (int k = 0; k < 96; ++k) {
        float w0 = W1s[k * 128 + c0], w1 = W1s[k * 128 + c1];
        a00 = fmaf(x0[k], w0, a00); a01 = fmaf(x0[k], w1, a01);
        a10 = fmaf(x1[k], w0, a10); a11 = fmaf(x1[k], w1, a11);
        a20 = fmaf(x2[k], w0, a20); a21 = fmaf(x2[k], w1, a21);
        a30 = fmaf(x3[k], w0, a30); a31 = fmaf(x3[k], w1, a31);
    }
#pragma unroll 4
    for (int k = 0; k < 96; ++k) {
        float w0 = W1n[k * 128 + c0], w1 = W1n[k * 128 + c1];
        a00 = fmaf(x0[96 + k], w0, a00); a01 = fmaf(x0[96 + k], w1, a01);
        a10 = fmaf(x1[96 + k], w0, a10); a11 = fmaf(x1[96 + k], w1, a11);
        a20 = fmaf(x2[96 + k], w0, a20); a21 = fmaf(x2[96 + k], w1, a21);
        a30 = fmaf(x3[96 + k], w0, a30); a31 = fmaf(x3[96 + k], w1, a31);
    }
    float accs[4][2] = {{a00, a01}, {a10, a11}, {a20, a21}, {a30, a31}};
#pragma unroll
    for (int rr = 0; rr < 4; ++rr) {
        int row = base + wv * 4 + rr;
        if (row < N) {
            h1[(size_t)row * 128 + c0] = fmaxf(accs[rr][0], 0.0f);
            h1[(size_t)row * 128 + c1] = fmaxf(accs[rr][1], 0.0f);
        }
    }
}

// ---------------- proj2: y2 = h1 @ W2n (128->64), 4 rows/wave ----------------
__global__ __launch_bounds__(256) void k_proj2(
    const float* __restrict__ h1, const float* __restrict__ W2n,
    float* __restrict__ y2, int N) {
    __shared__ float xs[16][128];
    int wv = threadIdx.x >> 6, lane = threadIdx.x & 63;
    int base = blockIdx.x * 16;
#pragma unroll
    for (int rr = 0; rr < 4; ++rr) {
        int row = base + wv * 4 + rr;
        int r = row < N ? row : N - 1;
        xs[wv * 4 + rr][lane]      = h1[(size_t)r * 128 + lane];
        xs[wv * 4 + rr][lane + 64] = h1[(size_t)r * 128 + lane + 64];
    }
    __syncthreads();
    const float* x0 = xs[wv * 4 + 0];
    const float* x1 = xs[wv * 4 + 1];
    const float* x2 = xs[wv * 4 + 2];
    const float* x3 = xs[wv * 4 + 3];
    float a0 = 0.0f, a1 = 0.0f, a2 = 0.0f, a3 = 0.0f;
#pragma unroll 4
    for (int k = 0; k < 128; ++k) {
        float w = W2n[k * 64 + lane];
        a0 = fmaf(x0[k], w, a0); a1 = fmaf(x1[k], w, a1);
        a2 = fmaf(x2[k], w, a2); a3 = fmaf(x3[k], w, a3);
    }
    float accs[4] = {a0, a1, a2, a3};
#pragma unroll
    for (int rr = 0; rr < 4; ++rr) {
        int row = base + wv * 4 + rr;
        if (row < N) y2[(size_t)row * 64 + lane] = accs[rr];
    }
}

// ---------------- layer-3 neighbor mean over y2 (64-wide), wave-per-node ----------------
__global__ __launch_bounds__(256) void k_gather64(
    const float* __restrict__ y2, const long long* __restrict__ eidsrc,
    const int* __restrict__ offsets, float* __restrict__ hn2p, int N) {
    int node = blockIdx.x * 4 + (threadIdx.x >> 6);
    int j = threadIdx.x & 63;
    if (node >= N) return;
    int s0 = offsets[node], s1 = offsets[node + 1];
    float ivn = 1.0f / (float)max(s1 - s0, 1);
    float sum = 0.0f;
    int i = s0;
    for (; i + 4 <= s1; i += 4) {
        int sa = (int)(eidsrc[i] >> 32);
        int sb = (int)(eidsrc[i + 1] >> 32);
        int sc = (int)(eidsrc[i + 2] >> 32);
        int sd = (int)(eidsrc[i + 3] >> 32);
        float va = y2[(size_t)sa * 64 + j];
        float vb = y2[(size_t)sb * 64 + j];
        float vc = y2[(size_t)sc * 64 + j];
        float vd = y2[(size_t)sd * 64 + j];
        sum += (va + vb) + (vc + vd);
    }
    for (; i < s1; ++i) sum += y2[(size_t)((int)(eidsrc[i] >> 32)) * 64 + j];
    hn2p[(size_t)node * 64 + j] = sum * ivn;
}

// ---------------- mm2b: out = h1@W2s + b2 + hn2p, 4 rows/wave ----------------
__global__ __launch_bounds__(256) void k_mm2b(
    const float* __restrict__ h1, const float* __restrict__ hn2p,
    const float* __restrict__ W2s, const float* __restrict__ b2,
    float* __restrict__ out, int N) {
    __shared__ float xs[16][128];
    int wv = threadIdx.x >> 6, lane = threadIdx.x & 63;
    int base = blockIdx.x * 16;
#pragma unroll
    for (int rr = 0; rr < 4; ++rr) {
        int row = base + wv * 4 + rr;
        int r = row < N ? row : N - 1;
        xs[wv * 4 + rr][lane]      = h1[(size_t)r * 128 + lane];
        xs[wv * 4 + rr][lane + 64] = h1[(size_t)r * 128 + lane + 64];
    }
    __syncthreads();
    const float* x0 = xs[wv * 4 + 0];
    const float* x1 = xs[wv * 4 + 1];
    const float* x2 = xs[wv * 4 + 2];
    const float* x3 = xs[wv * 4 + 3];
    float a0 = b2[lane], a1 = a0, a2 = a0, a3 = a0;
#pragma unroll 4
    for (int k = 0; k < 128; ++k) {
        float w = W2s[k * 64 + lane];
        a0 = fmaf(x0[k], w, a0); a1 = fmaf(x1[k], w, a1);
        a2 = fmaf(x2[k], w, a2); a3 = fmaf(x3[k], w, a3);
    }
    float accs[4] = {a0, a1, a2, a3};
#pragma unroll
    for (int rr = 0; rr < 4; ++rr) {
        int row = base + wv * 4 + rr;
        if (row < N) out[(size_t)row * 64 + lane] = accs[rr] + hn2p[(size_t)row * 64 + lane];
    }
}

extern "C" void kernel_launch(void* const* d_in, const int* in_sizes, int n_in,
                              void* d_out, int out_size, void* d_ws, size_t ws_size,
                              hipStream_t stream) {
    const float* nfeat = (const float*)d_in[0];
    const float* efeat = (const float*)d_in[1];
    const int*   src   = (const int*)d_in[2];
    const int*   dst   = (const int*)d_in[3];
    const float* We    = (const float*)d_in[4];
    const float* be    = (const float*)d_in[5];
    const float* W1s   = (const float*)d_in[6];
    const float* W1n   = (const float*)d_in[7];
    const float* b1    = (const float*)d_in[8];
    const float* W2s   = (const float*)d_in[9];
    const float* W2n   = (const float*)d_in[10];
    const float* b2    = (const float*)d_in[11];
    float* out = (float*)d_out;

    int N = in_sizes[0] / IN_F;
    int E = in_sizes[2];

    // workspace layout (4B units):
    // cursor[N] | offsets[N+64] | blksum[256] | eidsrc[2E] (8B-aligned) |
    // hcat[96N] | h1[128N] | msort[48E]
    // Aliased into the msort region after gather48m consumes it:
    //   hn1m = msort[0,96N) ; y2 = msort[96N,160N) ; hn2p = msort[160N,224N)
    //   (224N = 22.4M floats << 48E = 76.8M floats)
    int*       cursor  = (int*)d_ws;
    int*       offsets = cursor + N;
    int*       blksum  = offsets + N + 64;
    long long* eidsrc  = (long long*)(blksum + 256);   // N even -> 8B aligned
    float*     hcat    = (float*)(eidsrc + E);
    float*     h1      = hcat + (size_t)96 * N;
    float*     msort   = h1 + (size_t)128 * N;
    float*     hn1m    = msort;
    float*     y2      = msort + (size_t)96 * N;
    float*     hn2p    = msort + (size_t)160 * N;

    int nb = (N + 1023) / 1024;  // 98 for N=100000 (<=256 required by k_scan2)

    (void)hipMemsetAsync(cursor, 0, (size_t)N * sizeof(int), stream);
    k_hist<<<(E + 255) / 256, 256, 0, stream>>>(dst, cursor, E);
    k_scan1<<<nb, 1024, 0, stream>>>(cursor, offsets, blksum, N);   // also re-zeros cursor
    k_scan2<<<1, 256, 0, stream>>>(blksum, nb);
    k_scan3<<<nb, 1024, 0, stream>>>(offsets, blksum, N);

    k_fill<<<(E + 255) / 256, 256, 0, stream>>>(dst, src, offsets, cursor, eidsrc, E);
    k_edge_msg<<<(E + 255) / 256, 256, 0, stream>>>(efeat, nfeat, eidsrc, We, be, msort, E);
    k_gather48m<<<(N + 3) / 4, 256, 0, stream>>>(msort, nfeat, offsets, hcat, N);
    k_gather96<<<(N + 3) / 4, 256, 0, stream>>>(hcat, eidsrc, offsets, hn1m, N);
    k_mm1<<<(N + 15) / 16, 256, 0, stream>>>(hcat, hn1m, W1s, W1n, b1, h1, N);
    k_proj2<<<(N + 15) / 16, 256, 0, stream>>>(h1, W2n, y2, N);
    k_gather64<<<(N + 3) / 4, 256, 0, stream>>>(y2, eidsrc, offsets, hn2p, N);
    k_mm2b<<<(N + 15) / 16, 256, 0, stream>>>(h1, hn2p, W2s, b2, out, N);
}

// Round 7
// 1081.302 us; speedup vs baseline: 1.4622x; 1.4622x over previous
//
#include <hip/hip_runtime.h>

#define IN_F 48
#define EDGE_F 32
#define HID_F 128
#define OUT_F 64

// ---------------- counting-sort-by-dst preprocessing ----------------

__global__ void k_hist(const int* __restrict__ dst, int* __restrict__ cnt, int E) {
    int e = blockIdx.x * 256 + threadIdx.x;
    if (e < E) atomicAdd(&cnt[dst[e]], 1);
}

// inclusive scan of 1024-chunk -> offsets[1+g]; chunk totals -> blksum; zeroes cnt for reuse as cursor
__global__ void k_scan1(int* __restrict__ cnt, int* __restrict__ offsets,
                        int* __restrict__ blksum, int N) {
    __shared__ int sh[1024];
    int tid = threadIdx.x;
    int g = blockIdx.x * 1024 + tid;
    sh[tid] = (g < N) ? cnt[g] : 0;
    if (g < N) cnt[g] = 0;   // cursor reset folded in
    __syncthreads();
#pragma unroll
    for (int off = 1; off < 1024; off <<= 1) {
        int t = (tid >= off) ? sh[tid - off] : 0;
        __syncthreads();
        sh[tid] += t;
        __syncthreads();
    }
    if (g < N) offsets[1 + g] = sh[tid];
    if (tid == 1023) blksum[blockIdx.x] = sh[tid];
}

__global__ void k_scan2(int* __restrict__ blksum, int nb) {
    __shared__ int sh[256];
    int tid = threadIdx.x;
    int orig = (tid < nb) ? blksum[tid] : 0;
    sh[tid] = orig;
    __syncthreads();
#pragma unroll
    for (int off = 1; off < 256; off <<= 1) {
        int t = (tid >= off) ? sh[tid - off] : 0;
        __syncthreads();
        sh[tid] += t;
        __syncthreads();
    }
    if (tid < nb) blksum[tid] = sh[tid] - orig;  // exclusive
}

__global__ void k_scan3(int* __restrict__ offsets, const int* __restrict__ blksum, int N) {
    int g = blockIdx.x * 1024 + threadIdx.x;
    if (g < N) offsets[1 + g] += blksum[blockIdx.x];
    if (g == 0) offsets[0] = 0;
}

// ---------------- fill: one 8B scattered store per edge ----------------
__global__ void k_fill(const int* __restrict__ dst, const int* __restrict__ src,
                       const int* __restrict__ offsets, int* __restrict__ cursor,
                       long long* __restrict__ eidsrc, int E) {
    int e = blockIdx.x * 256 + threadIdx.x;
    if (e >= E) return;
    int d = dst[e];
    int s = src[e];
    int p = atomicAdd(&cursor[d], 1);
    int pos = offsets[d] + p;
    eidsrc[pos] = ((long long)s << 32) | (unsigned int)e;
}

// ---------------- edge encoder: random efeat read, sequential msort write ----------------
__global__ __launch_bounds__(256) void k_edge_msg(
    const float* __restrict__ efeat, const float* __restrict__ nfeat,
    const long long* __restrict__ eidsrc,
    const float* __restrict__ We, const float* __restrict__ be,
    float* __restrict__ msort, int E) {
    int i = blockIdx.x * 256 + threadIdx.x;
    if (i >= E) return;
    long long es = eidsrc[i];
    int e = (int)es;
    int s = (int)(es >> 32);

    float ef[EDGE_F];
    const float4* ef4 = (const float4*)(efeat + (size_t)e * EDGE_F);
#pragma unroll
    for (int q = 0; q < EDGE_F / 4; ++q) {
        float4 v = ef4[q];
        ef[4 * q + 0] = v.x; ef[4 * q + 1] = v.y; ef[4 * q + 2] = v.z; ef[4 * q + 3] = v.w;
    }
    float acc[IN_F];
#pragma unroll
    for (int j = 0; j < IN_F; ++j) acc[j] = be[j];          // wave-uniform -> s_load
#pragma unroll
    for (int k = 0; k < EDGE_F; ++k) {
        float ek = ef[k];
#pragma unroll
        for (int j = 0; j < IN_F; ++j) acc[j] = fmaf(ek, We[k * IN_F + j], acc[j]);
    }
    const float4* n4 = (const float4*)(nfeat + (size_t)s * IN_F);
    float4* o4 = (float4*)(msort + (size_t)i * IN_F);
#pragma unroll
    for (int q = 0; q < IN_F / 4; ++q) {
        float4 nv = n4[q];
        float4 ov;
        ov.x = fmaxf(acc[4 * q + 0], 0.0f) * nv.x;
        ov.y = fmaxf(acc[4 * q + 1], 0.0f) * nv.y;
        ov.z = fmaxf(acc[4 * q + 2], 0.0f) * nv.z;
        ov.w = fmaxf(acc[4 * q + 3], 0.0f) * nv.w;
        o4[q] = ov;
    }
}

// ---------------- layer-1 mean (stream msort) + build hcat=[nfeat,hn0] ----------------
__global__ __launch_bounds__(256) void k_gather48m(
    const float* __restrict__ msort, const float* __restrict__ nfeat,
    const int* __restrict__ offsets, float* __restrict__ hcat, int N) {
    int node = blockIdx.x * 4 + (threadIdx.x >> 6);
    int j = threadIdx.x & 63;
    if (node >= N) return;
    int jj = (j < IN_F) ? j : 0;
    int s0 = offsets[node], s1 = offsets[node + 1];
    float ivn = 1.0f / (float)max(s1 - s0, 1);
    float sum = 0.0f;
    int i = s0;
    for (; i + 4 <= s1; i += 4) {
        float a = msort[(size_t)(i + 0) * IN_F + jj];
        float b = msort[(size_t)(i + 1) * IN_F + jj];
        float c = msort[(size_t)(i + 2) * IN_F + jj];
        float d = msort[(size_t)(i + 3) * IN_F + jj];
        sum += (a + b) + (c + d);
    }
    for (; i < s1; ++i) sum += msort[(size_t)i * IN_F + jj];
    if (j < IN_F) {
        hcat[(size_t)node * 96 + IN_F + j] = sum * ivn;                // hn0 half
        hcat[(size_t)node * 96 + j] = nfeat[(size_t)node * IN_F + j];  // nfeat half
    }
}

// ---------------- layer-2 neighbor mean over hcat (96-wide), wave-per-node ----------------
// lane j owns col j; lanes j<32 additionally own col 64+j.
__global__ __launch_bounds__(256) void k_gather96(
    const float* __restrict__ hcat, const long long* __restrict__ eidsrc,
    const int* __restrict__ offsets, float* __restrict__ hn1m, int N) {
    int node = blockIdx.x * 4 + (threadIdx.x >> 6);
    int j = threadIdx.x & 63;
    if (node >= N) return;
    const float* tabA = hcat + j;         // cols 0..63
    const float* tabB = hcat + 64 + j;    // cols 64..95 (j<32)
    int s0 = offsets[node], s1 = offsets[node + 1];
    float ivn = 1.0f / (float)max(s1 - s0, 1);
    float sA = 0.0f, sB = 0.0f;
    int i = s0;
    for (; i + 4 <= s1; i += 4) {
        int sa = (int)(eidsrc[i] >> 32);
        int sb = (int)(eidsrc[i + 1] >> 32);
        int sc = (int)(eidsrc[i + 2] >> 32);
        int sd = (int)(eidsrc[i + 3] >> 32);
        float a0 = tabA[(size_t)sa * 96], a1 = tabA[(size_t)sb * 96];
        float a2 = tabA[(size_t)sc * 96], a3 = tabA[(size_t)sd * 96];
        sA += (a0 + a1) + (a2 + a3);
        if (j < 32) {
            float b0 = tabB[(size_t)sa * 96], b1 = tabB[(size_t)sb * 96];
            float b2 = tabB[(size_t)sc * 96], b3 = tabB[(size_t)sd * 96];
            sB += (b0 + b1) + (b2 + b3);
        }
    }
    for (; i < s1; ++i) {
        int sa = (int)(eidsrc[i] >> 32);
        sA += tabA[(size_t)sa * 96];
        if (j < 32) sB += tabB[(size_t)sa * 96];
    }
    hn1m[(size_t)node * 96 + j] = sA * ivn;
    if (j < 32) hn1m[(size_t)node * 96 + 64 + j] = sB * ivn;
}

// ---------------- mm1: h1 = relu(hcat@W1s + hn1m@W1n + b1), 4 rows/wave ----------------
__global__ __launch_bounds__(256) void k_mm1(
    const float* __restrict__ hcat, const float* __restrict__ hn1m,
    const float* __restrict__ W1s, const float* __restrict__ W1n,
    const float* __restrict__ b1, float* __restrict__ h1, int N) {
    __shared__ float xs[16][192];
    int wv = threadIdx.x >> 6, lane = threadIdx.x & 63;
    int base = blockIdx.x * 16;
#pragma unroll
    for (int rr = 0; rr < 4; ++rr) {
        int row = base + wv * 4 + rr;
        int r = row < N ? row : N - 1;
#pragma unroll
        for (int kk = 0; kk < 3; ++kk) {
            int k = lane + kk * 64;
            float v = (k < 96) ? hcat[(size_t)r * 96 + k] : hn1m[(size_t)r * 96 + (k - 96)];
            xs[wv * 4 + rr][k] = v;
        }
    }
    __syncthreads();
    const float* x0 = xs[wv * 4 + 0];
    const float* x1 = xs[wv * 4 + 1];
    const float* x2 = xs[wv * 4 + 2];
    const float* x3 = xs[wv * 4 + 3];
    int c0 = lane, c1 = lane + 64;
    float a00 = b1[c0], a01 = b1[c1];
    float a10 = a00, a11 = a01, a20 = a00, a21 = a01, a30 = a00, a31 = a01;
#pragma unroll 4
    for (int k = 0; k < 96; ++k) {
        float w0 = W1s[k * 128 + c0], w1 = W1s[k * 128 + c1];
        a00 = fmaf(x0[k], w0, a00); a01 = fmaf(x0[k], w1, a01);
        a10 = fmaf(x1[k], w0, a10); a11 = fmaf(x1[k], w1, a11);
        a20 = fmaf(x2[k], w0, a20); a21 = fmaf(x2[k], w1, a21);
        a30 = fmaf(x3[k], w0, a30); a31 = fmaf(x3[k], w1, a31);
    }
#pragma unroll 4
    for (int k = 0; k < 96; ++k) {
        float w0 = W1n[k * 128 + c0], w1 = W1n[k * 128 + c1];
        a00 = fmaf(x0[96 + k], w0, a00); a01 = fmaf(x0[96 + k], w1, a01);
        a10 = fmaf(x1[96 + k], w0, a10); a11 = fmaf(x1[96 + k], w1, a11);
        a20 = fmaf(x2[96 + k], w0, a20); a21 = fmaf(x2[96 + k], w1, a21);
        a30 = fmaf(x3[96 + k], w0, a30); a31 = fmaf(x3[96 + k], w1, a31);
    }
    float accs[4][2] = {{a00, a01}, {a10, a11}, {a20, a21}, {a30, a31}};
#pragma unroll
    for (int rr = 0; rr < 4; ++rr) {
        int row = base + wv * 4 + rr;
        if (row < N) {
            h1[(size_t)row * 128 + c0] = fmaxf(accs[rr][0], 0.0f);
            h1[(size_t)row * 128 + c1] = fmaxf(accs[rr][1], 0.0f);
        }
    }
}

// ---------------- proj2: y2 = h1 @ W2n (128->64), 4 rows/wave ----------------
__global__ __launch_bounds__(256) void k_proj2(
    const float* __restrict__ h1, const float* __restrict__ W2n,
    float* __restrict__ y2, int N) {
    __shared__ float xs[16][128];
    int wv = threadIdx.x >> 6, lane = threadIdx.x & 63;
    int base = blockIdx.x * 16;
#pragma unroll
    for (int rr = 0; rr < 4; ++rr) {
        int row = base + wv * 4 + rr;
        int r = row < N ? row : N - 1;
        xs[wv * 4 + rr][lane]      = h1[(size_t)r * 128 + lane];
        xs[wv * 4 + rr][lane + 64] = h1[(size_t)r * 128 + lane + 64];
    }
    __syncthreads();
    const float* x0 = xs[wv * 4 + 0];
    const float* x1 = xs[wv * 4 + 1];
    const float* x2 = xs[wv * 4 + 2];
    const float* x3 = xs[wv * 4 + 3];
    float a0 = 0.0f, a1 = 0.0f, a2 = 0.0f, a3 = 0.0f;
#pragma unroll 4
    for (int k = 0; k < 128; ++k) {
        float w = W2n[k * 64 + lane];
        a0 = fmaf(x0[k], w, a0); a1 = fmaf(x1[k], w, a1);
        a2 = fmaf(x2[k], w, a2); a3 = fmaf(x3[k], w, a3);
    }
    float accs[4] = {a0, a1, a2, a3};
#pragma unroll
    for (int rr = 0; rr < 4; ++rr) {
        int row = base + wv * 4 + rr;
        if (row < N) y2[(size_t)row * 64 + lane] = accs[rr];
    }
}

// ---------------- layer-3 neighbor mean over y2 (64-wide), wave-per-node ----------------
__global__ __launch_bounds__(256) void k_gather64(
    const float* __restrict__ y2, const long long* __restrict__ eidsrc,
    const int* __restrict__ offsets, float* __restrict__ hn2p, int N) {
    int node = blockIdx.x * 4 + (threadIdx.x >> 6);
    int j = threadIdx.x & 63;
    if (node >= N) return;
    int s0 = offsets[node], s1 = offsets[node + 1];
    float ivn = 1.0f / (float)max(s1 - s0, 1);
    float sum = 0.0f;
    int i = s0;
    for (; i + 4 <= s1; i += 4) {
        int sa = (int)(eidsrc[i] >> 32);
        int sb = (int)(eidsrc[i + 1] >> 32);
        int sc = (int)(eidsrc[i + 2] >> 32);
        int sd = (int)(eidsrc[i + 3] >> 32);
        float va = y2[(size_t)sa * 64 + j];
        float vb = y2[(size_t)sb * 64 + j];
        float vc = y2[(size_t)sc * 64 + j];
        float vd = y2[(size_t)sd * 64 + j];
        sum += (va + vb) + (vc + vd);
    }
    for (; i < s1; ++i) sum += y2[(size_t)((int)(eidsrc[i] >> 32)) * 64 + j];
    hn2p[(size_t)node * 64 + j] = sum * ivn;
}

// ---------------- mm2b: out = h1@W2s + b2 + hn2p, 4 rows/wave ----------------
__global__ __launch_bounds__(256) void k_mm2b(
    const float* __restrict__ h1, const float* __restrict__ hn2p,
    const float* __restrict__ W2s, const float* __restrict__ b2,
    float* __restrict__ out, int N) {
    __shared__ float xs[16][128];
    int wv = threadIdx.x >> 6, lane = threadIdx.x & 63;
    int base = blockIdx.x * 16;
#pragma unroll
    for (int rr = 0; rr < 4; ++rr) {
        int row = base + wv * 4 + rr;
        int r = row < N ? row : N - 1;
        xs[wv * 4 + rr][lane]      = h1[(size_t)r * 128 + lane];
        xs[wv * 4 + rr][lane + 64] = h1[(size_t)r * 128 + lane + 64];
    }
    __syncthreads();
    const float* x0 = xs[wv * 4 + 0];
    const float* x1 = xs[wv * 4 + 1];
    const float* x2 = xs[wv * 4 + 2];
    const float* x3 = xs[wv * 4 + 3];
    float a0 = b2[lane], a1 = a0, a2 = a0, a3 = a0;
#pragma unroll 4
    for (int k = 0; k < 128; ++k) {
        float w = W2s[k * 64 + lane];
        a0 = fmaf(x0[k], w, a0); a1 = fmaf(x1[k], w, a1);
        a2 = fmaf(x2[k], w, a2); a3 = fmaf(x3[k], w, a3);
    }
    float accs[4] = {a0, a1, a2, a3};
#pragma unroll
    for (int rr = 0; rr < 4; ++rr) {
        int row = base + wv * 4 + rr;
        if (row < N) out[(size_t)row * 64 + lane] = accs[rr] + hn2p[(size_t)row * 64 + lane];
    }
}

extern "C" void kernel_launch(void* const* d_in, const int* in_sizes, int n_in,
                              void* d_out, int out_size, void* d_ws, size_t ws_size,
                              hipStream_t stream) {
    const float* nfeat = (const float*)d_in[0];
    const float* efeat = (const float*)d_in[1];
    const int*   src   = (const int*)d_in[2];
    const int*   dst   = (const int*)d_in[3];
    const float* We    = (const float*)d_in[4];
    const float* be    = (const float*)d_in[5];
    const float* W1s   = (const float*)d_in[6];
    const float* W1n   = (const float*)d_in[7];
    const float* b1    = (const float*)d_in[8];
    const float* W2s   = (const float*)d_in[9];
    const float* W2n   = (const float*)d_in[10];
    const float* b2    = (const float*)d_in[11];
    float* out = (float*)d_out;

    int N = in_sizes[0] / IN_F;
    int E = in_sizes[2];

    // workspace layout (4B units):
    // cursor[N] | offsets[N+64] | blksum[256] | eidsrc[2E] (8B-aligned) |
    // hcat[96N] | h1[128N] | msort[48E]
    // Aliased into the msort region after gather48m consumes it:
    //   hn1m = msort[0,96N) ; y2 = msort[96N,160N) ; hn2p = msort[160N,224N)
    //   (224N = 22.4M floats << 48E = 76.8M floats)
    int*       cursor  = (int*)d_ws;
    int*       offsets = cursor + N;
    int*       blksum  = offsets + N + 64;
    long long* eidsrc  = (long long*)(blksum + 256);   // N even -> 8B aligned
    float*     hcat    = (float*)(eidsrc + E);
    float*     h1      = hcat + (size_t)96 * N;
    float*     msort   = h1 + (size_t)128 * N;
    float*     hn1m    = msort;
    float*     y2      = msort + (size_t)96 * N;
    float*     hn2p    = msort + (size_t)160 * N;

    int nb = (N + 1023) / 1024;  // 98 for N=100000 (<=256 required by k_scan2)

    (void)hipMemsetAsync(cursor, 0, (size_t)N * sizeof(int), stream);
    k_hist<<<(E + 255) / 256, 256, 0, stream>>>(dst, cursor, E);
    k_scan1<<<nb, 1024, 0, stream>>>(cursor, offsets, blksum, N);   // also re-zeros cursor
    k_scan2<<<1, 256, 0, stream>>>(blksum, nb);
    k_scan3<<<nb, 1024, 0, stream>>>(offsets, blksum, N);

    k_fill<<<(E + 255) / 256, 256, 0, stream>>>(dst, src, offsets, cursor, eidsrc, E);
    k_edge_msg<<<(E + 255) / 256, 256, 0, stream>>>(efeat, nfeat, eidsrc, We, be, msort, E);
    k_gather48m<<<(N + 3) / 4, 256, 0, stream>>>(msort, nfeat, offsets, hcat, N);
    k_gather96<<<(N + 3) / 4, 256, 0, stream>>>(hcat, eidsrc, offsets, hn1m, N);
    k_mm1<<<(N + 15) / 16, 256, 0, stream>>>(hcat, hn1m, W1s, W1n, b1, h1, N);
    k_proj2<<<(N + 15) / 16, 256, 0, stream>>>(h1, W2n, y2, N);
    k_gather64<<<(N + 3) / 4, 256, 0, stream>>>(y2, eidsrc, offsets, hn2p, N);
    k_mm2b<<<(N + 15) / 16, 256, 0, stream>>>(h1, hn2p, W2s, b2, out, N);
}

// Round 8
// 902.175 us; speedup vs baseline: 1.7525x; 1.1986x over previous
//
#include <hip/hip_runtime.h>

#define IN_F 48
#define EDGE_F 32
#define HID_F 128
#define OUT_F 64

// pack layout: e in bits [0,21), s in [21,42), d in [42,63).  Requires N,E < 2^21.

// ---------------- counting-sort-by-dst preprocessing ----------------

__global__ void k_hist(const int* __restrict__ dst, int* __restrict__ cnt, int E) {
    int e = blockIdx.x * 256 + threadIdx.x;
    if (e < E) atomicAdd(&cnt[dst[e]], 1);
}

// inclusive scan of 1024-chunk -> offsets[1+g]; chunk totals -> blksum; zeroes cnt for reuse as cursor
__global__ void k_scan1(int* __restrict__ cnt, int* __restrict__ offsets,
                        int* __restrict__ blksum, int N) {
    __shared__ int sh[1024];
    int tid = threadIdx.x;
    int g = blockIdx.x * 1024 + tid;
    sh[tid] = (g < N) ? cnt[g] : 0;
    if (g < N) cnt[g] = 0;   // cursor reset folded in
    __syncthreads();
#pragma unroll
    for (int off = 1; off < 1024; off <<= 1) {
        int t = (tid >= off) ? sh[tid - off] : 0;
        __syncthreads();
        sh[tid] += t;
        __syncthreads();
    }
    if (g < N) offsets[1 + g] = sh[tid];
    if (tid == 1023) blksum[blockIdx.x] = sh[tid];
}

__global__ void k_scan2(int* __restrict__ blksum, int nb) {
    __shared__ int sh[256];
    int tid = threadIdx.x;
    int orig = (tid < nb) ? blksum[tid] : 0;
    sh[tid] = orig;
    __syncthreads();
#pragma unroll
    for (int off = 1; off < 256; off <<= 1) {
        int t = (tid >= off) ? sh[tid - off] : 0;
        __syncthreads();
        sh[tid] += t;
        __syncthreads();
    }
    if (tid < nb) blksum[tid] = sh[tid] - orig;  // exclusive
}

__global__ void k_scan3(int* __restrict__ offsets, const int* __restrict__ blksum, int N) {
    int g = blockIdx.x * 1024 + threadIdx.x;
    if (g < N) offsets[1 + g] += blksum[blockIdx.x];
    if (g == 0) offsets[0] = 0;
}

// ---------------- fill: one 8B scattered store per edge, (d,s,e) packed ----------------
__global__ void k_fill(const int* __restrict__ dst, const int* __restrict__ src,
                       const int* __restrict__ offsets, int* __restrict__ cursor,
                       unsigned long long* __restrict__ pack, int E) {
    int e = blockIdx.x * 256 + threadIdx.x;
    if (e >= E) return;
    int d = dst[e];
    int s = src[e];
    int p = atomicAdd(&cursor[d], 1);
    int pos = offsets[d] + p;
    pack[pos] = ((unsigned long long)d << 42) | ((unsigned long long)s << 21) | (unsigned long long)e;
}

// ---------------- fused edge encoder + in-LDS segment reduction ----------------
// Block owns 256 consecutive sorted positions. Messages -> LDS; runs of equal d
// summed by waves; complete runs plain-store, block-edge-cut runs atomicAdd.
__global__ __launch_bounds__(256) void k_edge_reduce(
    const float* __restrict__ efeat, const float* __restrict__ nfeat,
    const unsigned long long* __restrict__ pack,
    const float* __restrict__ We, const float* __restrict__ be,
    float* __restrict__ hn0sum, int E)
{
    __shared__ float lmsg[256][49];   // pad 49: conflict-free col reads & row writes
    __shared__ int ld[256];
    __shared__ unsigned long long hm[4];
    __shared__ int dnb[2];            // d of global predecessor / successor
    int tid = threadIdx.x;
    int B0 = blockIdx.x * 256;
    int i = B0 + tid;
    int nvalid = min(256, E - B0);
    if (tid == 0) {
        dnb[0] = (B0 > 0) ? (int)(pack[B0 - 1] >> 42) : -9;
        dnb[1] = (B0 + 256 < E) ? (int)(pack[B0 + 256] >> 42) : -9;
    }
    int d = -3;
    if (i < E) {
        unsigned long long v = pack[i];
        int e = (int)(v & 0x1FFFFF);
        int s = (int)((v >> 21) & 0x1FFFFF);
        d = (int)(v >> 42);

        float ef[EDGE_F];
        const float4* ef4 = (const float4*)(efeat + (size_t)e * EDGE_F);
#pragma unroll
        for (int q = 0; q < EDGE_F / 4; ++q) {
            float4 t = ef4[q];
            ef[4 * q + 0] = t.x; ef[4 * q + 1] = t.y; ef[4 * q + 2] = t.z; ef[4 * q + 3] = t.w;
        }
        float acc[IN_F];
#pragma unroll
        for (int j = 0; j < IN_F; ++j) acc[j] = be[j];          // wave-uniform -> s_load
#pragma unroll
        for (int k = 0; k < EDGE_F; ++k) {
            float ek = ef[k];
#pragma unroll
            for (int j = 0; j < IN_F; ++j) acc[j] = fmaf(ek, We[k * IN_F + j], acc[j]);
        }
        const float4* n4 = (const float4*)(nfeat + (size_t)s * IN_F);
#pragma unroll
        for (int q = 0; q < IN_F / 4; ++q) {
            float4 nv = n4[q];
            lmsg[tid][4 * q + 0] = fmaxf(acc[4 * q + 0], 0.0f) * nv.x;
            lmsg[tid][4 * q + 1] = fmaxf(acc[4 * q + 1], 0.0f) * nv.y;
            lmsg[tid][4 * q + 2] = fmaxf(acc[4 * q + 2], 0.0f) * nv.z;
            lmsg[tid][4 * q + 3] = fmaxf(acc[4 * q + 3], 0.0f) * nv.w;
        }
    }
    ld[tid] = d;
    __syncthreads();

    bool head = (i < E) && (tid == 0 || d != ld[tid - 1]);
    unsigned long long m = __ballot(head);
    int wv = tid >> 6, lane = tid & 63;
    if (lane == 0) hm[wv] = m;
    __syncthreads();

    int dprev = dnb[0], dnext = dnb[1];
    unsigned long long mym = hm[wv];
    while (mym) {
        int rel = __ffsll(mym) - 1;
        mym &= mym - 1;
        int a = wv * 64 + rel;
        // find next head strictly after a
        int b = nvalid;
        {
            unsigned long long mm = (rel < 63) ? (hm[wv] & (~0ULL << (rel + 1))) : 0ULL;
            int w2 = wv;
            while (true) {
                if (mm) { b = w2 * 64 + __ffsll(mm) - 1; break; }
                if (++w2 >= 4) break;
                mm = hm[w2];
            }
        }
        int dd = ld[a];
        bool cut = (a == 0 && dd == dprev) || (b == nvalid && dd == dnext);
        if (lane < IN_F) {
            float sum = 0.0f;
            for (int t = a; t < b; ++t) sum += lmsg[t][lane];
            float* dp = hn0sum + (size_t)dd * IN_F + lane;
            if (cut) atomicAdd(dp, sum);
            else *dp = sum;
        }
    }
}

// ---------------- hcat builder: hcat = [nfeat, hn0sum/deg] ----------------
__global__ void k_hcatb(const float* __restrict__ nfeat, const float* __restrict__ hn0sum,
                        const int* __restrict__ offsets, float* __restrict__ hcat, int N) {
    int idx = blockIdx.x * 256 + threadIdx.x;
    int total = N * 12;
    if (idx >= total) return;
    int node = idx / 12;
    int q = idx - node * 12;
    float4 nv = ((const float4*)nfeat)[idx];
    float4 hv = ((const float4*)hn0sum)[idx];
    int deg = offsets[node + 1] - offsets[node];
    float ivn = 1.0f / (float)max(deg, 1);
    float4* out4 = (float4*)(hcat + (size_t)node * 96);
    out4[q] = nv;
    float4 o;
    o.x = hv.x * ivn; o.y = hv.y * ivn; o.z = hv.z * ivn; o.w = hv.w * ivn;
    out4[12 + q] = o;
}

// ---------------- layer-2 neighbor mean over hcat (96-wide), wave-per-node ----------------
__global__ __launch_bounds__(256) void k_gather96(
    const float* __restrict__ hcat, const unsigned long long* __restrict__ pack,
    const int* __restrict__ offsets, float* __restrict__ hn1m, int N) {
    int node = blockIdx.x * 4 + (threadIdx.x >> 6);
    int j = threadIdx.x & 63;
    if (node >= N) return;
    const float* tabA = hcat + j;         // cols 0..63
    const float* tabB = hcat + 64 + j;    // cols 64..95 (j<32)
    int s0 = offsets[node], s1 = offsets[node + 1];
    float ivn = 1.0f / (float)max(s1 - s0, 1);
    float sA = 0.0f, sB = 0.0f;
    int i = s0;
    for (; i + 4 <= s1; i += 4) {
        int sa = (int)((pack[i] >> 21) & 0x1FFFFF);
        int sb = (int)((pack[i + 1] >> 21) & 0x1FFFFF);
        int sc = (int)((pack[i + 2] >> 21) & 0x1FFFFF);
        int sd = (int)((pack[i + 3] >> 21) & 0x1FFFFF);
        float a0 = tabA[(size_t)sa * 96], a1 = tabA[(size_t)sb * 96];
        float a2 = tabA[(size_t)sc * 96], a3 = tabA[(size_t)sd * 96];
        sA += (a0 + a1) + (a2 + a3);
        if (j < 32) {
            float b0 = tabB[(size_t)sa * 96], b1 = tabB[(size_t)sb * 96];
            float b2 = tabB[(size_t)sc * 96], b3 = tabB[(size_t)sd * 96];
            sB += (b0 + b1) + (b2 + b3);
        }
    }
    for (; i < s1; ++i) {
        int sa = (int)((pack[i] >> 21) & 0x1FFFFF);
        sA += tabA[(size_t)sa * 96];
        if (j < 32) sB += tabB[(size_t)sa * 96];
    }
    hn1m[(size_t)node * 96 + j] = sA * ivn;
    if (j < 32) hn1m[(size_t)node * 96 + 64 + j] = sB * ivn;
}

// ---------------- mm1p: h1 = relu(hcat@W1s + hn1m@W1n + b1); y2 = h1@W2n ----------------
__global__ __launch_bounds__(256) void k_mm1p(
    const float* __restrict__ hcat, const float* __restrict__ hn1m,
    const float* __restrict__ W1s, const float* __restrict__ W1n,
    const float* __restrict__ b1, const float* __restrict__ W2n,
    float* __restrict__ h1, float* __restrict__ y2, int N) {
    __shared__ float xs[16][192];
    __shared__ float hs[16][128];
    int wv = threadIdx.x >> 6, lane = threadIdx.x & 63;
    int base = blockIdx.x * 16;
#pragma unroll
    for (int rr = 0; rr < 4; ++rr) {
        int row = base + wv * 4 + rr;
        int r = row < N ? row : N - 1;
#pragma unroll
        for (int kk = 0; kk < 3; ++kk) {
            int k = lane + kk * 64;
            float v = (k < 96) ? hcat[(size_t)r * 96 + k] : hn1m[(size_t)r * 96 + (k - 96)];
            xs[wv * 4 + rr][k] = v;
        }
    }
    __syncthreads();
    const float* x0 = xs[wv * 4 + 0];
    const float* x1 = xs[wv * 4 + 1];
    const float* x2 = xs[wv * 4 + 2];
    const float* x3 = xs[wv * 4 + 3];
    int c0 = lane, c1 = lane + 64;
    float a00 = b1[c0], a01 = b1[c1];
    float a10 = a00, a11 = a01, a20 = a00, a21 = a01, a30 = a00, a31 = a01;
#pragma unroll 4
    for (int k = 0; k < 96; ++k) {
        float w0 = W1s[k * 128 + c0], w1 = W1s[k * 128 + c1];
        a00 = fmaf(x0[k], w0, a00); a01 = fmaf(x0[k], w1, a01);
        a10 = fmaf(x1[k], w0, a10); a11 = fmaf(x1[k], w1, a11);
        a20 = fmaf(x2[k], w0, a20); a21 = fmaf(x2[k], w1, a21);
        a30 = fmaf(x3[k], w0, a30); a31 = fmaf(x3[k], w1, a31);
    }
#pragma unroll 4
    for (int k = 0; k < 96; ++k) {
        float w0 = W1n[k * 128 + c0], w1 = W1n[k * 128 + c1];
        a00 = fmaf(x0[96 + k], w0, a00); a01 = fmaf(x0[96 + k], w1, a01);
        a10 = fmaf(x1[96 + k], w0, a10); a11 = fmaf(x1[96 + k], w1, a11);
        a20 = fmaf(x2[96 + k], w0, a20); a21 = fmaf(x2[96 + k], w1, a21);
        a30 = fmaf(x3[96 + k], w0, a30); a31 = fmaf(x3[96 + k], w1, a31);
    }
    float accs[4][2] = {{a00, a01}, {a10, a11}, {a20, a21}, {a30, a31}};
#pragma unroll
    for (int rr = 0; rr < 4; ++rr) {
        int row = base + wv * 4 + rr;
        float v0 = fmaxf(accs[rr][0], 0.0f);
        float v1 = fmaxf(accs[rr][1], 0.0f);
        hs[wv * 4 + rr][c0] = v0;      // same-wave LDS write/read: no barrier needed
        hs[wv * 4 + rr][c1] = v1;
        if (row < N) {
            h1[(size_t)row * 128 + c0] = v0;
            h1[(size_t)row * 128 + c1] = v1;
        }
    }
    // projection: y2 = h1 @ W2n (128 -> 64), rows stay in LDS
    const float* p0 = hs[wv * 4 + 0];
    const float* p1 = hs[wv * 4 + 1];
    const float* p2 = hs[wv * 4 + 2];
    const float* p3 = hs[wv * 4 + 3];
    float q0 = 0.0f, q1 = 0.0f, q2 = 0.0f, q3 = 0.0f;
#pragma unroll 4
    for (int k = 0; k < 128; ++k) {
        float w = W2n[k * 64 + lane];
        q0 = fmaf(p0[k], w, q0); q1 = fmaf(p1[k], w, q1);
        q2 = fmaf(p2[k], w, q2); q3 = fmaf(p3[k], w, q3);
    }
    float qs[4] = {q0, q1, q2, q3};
#pragma unroll
    for (int rr = 0; rr < 4; ++rr) {
        int row = base + wv * 4 + rr;
        if (row < N) y2[(size_t)row * 64 + lane] = qs[rr];
    }
}

// ---------------- layer-3 neighbor mean over y2 (64-wide), wave-per-node ----------------
__global__ __launch_bounds__(256) void k_gather64(
    const float* __restrict__ y2, const unsigned long long* __restrict__ pack,
    const int* __restrict__ offsets, float* __restrict__ hn2p, int N) {
    int node = blockIdx.x * 4 + (threadIdx.x >> 6);
    int j = threadIdx.x & 63;
    if (node >= N) return;
    int s0 = offsets[node], s1 = offsets[node + 1];
    float ivn = 1.0f / (float)max(s1 - s0, 1);
    float sum = 0.0f;
    int i = s0;
    for (; i + 4 <= s1; i += 4) {
        int sa = (int)((pack[i] >> 21) & 0x1FFFFF);
        int sb = (int)((pack[i + 1] >> 21) & 0x1FFFFF);
        int sc = (int)((pack[i + 2] >> 21) & 0x1FFFFF);
        int sd = (int)((pack[i + 3] >> 21) & 0x1FFFFF);
        float va = y2[(size_t)sa * 64 + j];
        float vb = y2[(size_t)sb * 64 + j];
        float vc = y2[(size_t)sc * 64 + j];
        float vd = y2[(size_t)sd * 64 + j];
        sum += (va + vb) + (vc + vd);
    }
    for (; i < s1; ++i) sum += y2[(size_t)((pack[i] >> 21) & 0x1FFFFF) * 64 + j];
    hn2p[(size_t)node * 64 + j] = sum * ivn;
}

// ---------------- mm2b: out = h1@W2s + b2 + hn2p, 4 rows/wave ----------------
__global__ __launch_bounds__(256) void k_mm2b(
    const float* __restrict__ h1, const float* __restrict__ hn2p,
    const float* __restrict__ W2s, const float* __restrict__ b2,
    float* __restrict__ out, int N) {
    __shared__ float xs[16][128];
    int wv = threadIdx.x >> 6, lane = threadIdx.x & 63;
    int base = blockIdx.x * 16;
#pragma unroll
    for (int rr = 0; rr < 4; ++rr) {
        int row = base + wv * 4 + rr;
        int r = row < N ? row : N - 1;
        xs[wv * 4 + rr][lane]      = h1[(size_t)r * 128 + lane];
        xs[wv * 4 + rr][lane + 64] = h1[(size_t)r * 128 + lane + 64];
    }
    __syncthreads();
    const float* x0 = xs[wv * 4 + 0];
    const float* x1 = xs[wv * 4 + 1];
    const float* x2 = xs[wv * 4 + 2];
    const float* x3 = xs[wv * 4 + 3];
    float a0 = b2[lane], a1 = a0, a2 = a0, a3 = a0;
#pragma unroll 4
    for (int k = 0; k < 128; ++k) {
        float w = W2s[k * 64 + lane];
        a0 = fmaf(x0[k], w, a0); a1 = fmaf(x1[k], w, a1);
        a2 = fmaf(x2[k], w, a2); a3 = fmaf(x3[k], w, a3);
    }
    float accs[4] = {a0, a1, a2, a3};
#pragma unroll
    for (int rr = 0; rr < 4; ++rr) {
        int row = base + wv * 4 + rr;
        if (row < N) out[(size_t)row * 64 + lane] = accs[rr] + hn2p[(size_t)row * 64 + lane];
    }
}

extern "C" void kernel_launch(void* const* d_in, const int* in_sizes, int n_in,
                              void* d_out, int out_size, void* d_ws, size_t ws_size,
                              hipStream_t stream) {
    const float* nfeat = (const float*)d_in[0];
    const float* efeat = (const float*)d_in[1];
    const int*   src   = (const int*)d_in[2];
    const int*   dst   = (const int*)d_in[3];
    const float* We    = (const float*)d_in[4];
    const float* be    = (const float*)d_in[5];
    const float* W1s   = (const float*)d_in[6];
    const float* W1n   = (const float*)d_in[7];
    const float* b1    = (const float*)d_in[8];
    const float* W2s   = (const float*)d_in[9];
    const float* W2n   = (const float*)d_in[10];
    const float* b2    = (const float*)d_in[11];
    float* out = (float*)d_out;

    int N = in_sizes[0] / IN_F;
    int E = in_sizes[2];

    // workspace layout (4B words):
    // cursor[N] | hn0sum[48N] | offsets[N+64] | blksum[256] | pack[2E] |
    // hcat[96N] | h1[128N] | y2[64N] | hn1m[96N] | hn2p[64N]
    // single memset covers cursor+hn0sum (contiguous 49N)
    int*                cursor  = (int*)d_ws;
    float*              hn0sum  = (float*)(cursor + N);
    int*                offsets = (int*)(hn0sum + (size_t)48 * N);
    int*                blksum  = offsets + N + 64;
    unsigned long long* pack    = (unsigned long long*)(blksum + 256);  // N even -> 8B aligned
    float*              hcat    = (float*)(pack + E);
    float*              h1      = hcat + (size_t)96 * N;
    float*              y2      = h1 + (size_t)128 * N;
    float*              hn1m    = y2 + (size_t)64 * N;
    float*              hn2p    = hn1m + (size_t)96 * N;

    int nb = (N + 1023) / 1024;  // 98 for N=100000 (<=256 required by k_scan2)

    (void)hipMemsetAsync(cursor, 0, (size_t)49 * N * sizeof(float), stream);
    k_hist<<<(E + 255) / 256, 256, 0, stream>>>(dst, cursor, E);
    k_scan1<<<nb, 1024, 0, stream>>>(cursor, offsets, blksum, N);   // also re-zeros cursor
    k_scan2<<<1, 256, 0, stream>>>(blksum, nb);
    k_scan3<<<nb, 1024, 0, stream>>>(offsets, blksum, N);

    k_fill<<<(E + 255) / 256, 256, 0, stream>>>(dst, src, offsets, cursor, pack, E);
    k_edge_reduce<<<(E + 255) / 256, 256, 0, stream>>>(efeat, nfeat, pack, We, be, hn0sum, E);
    k_hcatb<<<(N * 12 + 255) / 256, 256, 0, stream>>>(nfeat, hn0sum, offsets, hcat, N);
    k_gather96<<<(N + 3) / 4, 256, 0, stream>>>(hcat, pack, offsets, hn1m, N);
    k_mm1p<<<(N + 15) / 16, 256, 0, stream>>>(hcat, hn1m, W1s, W1n, b1, W2n, h1, y2, N);
    k_gather64<<<(N + 3) / 4, 256, 0, stream>>>(y2, pack, offsets, hn2p, N);
    k_mm2b<<<(N + 15) / 16, 256, 0, stream>>>(h1, hn2p, W2s, b2, out, N);
}